// Round 5
// baseline (684.231 us; speedup 1.0000x reference)
//
#include <hip/hip_runtime.h>

#define LN_EPS 1e-5f
#define LOG2E 1.44269504f
#define NHALF_LOG2E (-0.72134752f)

#if __has_builtin(__builtin_amdgcn_exp2f)
#define EXP2F(x) __builtin_amdgcn_exp2f(x)
#else
#define EXP2F(x) __expf((x) * 0.69314718f)
#endif

// Megakernel: transpose -> wav0 -> ln0 -> wav1 -> ln1 -> wav2 -> ln2+cls.
// Round-4 lesson: barrier fixes hit diminishing returns (615->166->136); the
// residual stall is phase memory latency at 8 waves/CU (2/SIMD) -- the old
// 7-kernel wav_layer ran 32 waves/CU. Fix: occupancy. 2048 blocks x 256 thr,
// __launch_bounds__(256,8) caps VGPR at 64 (have ~44), LDS ~12.5KB/block ->
// 8 blocks/CU = 32 waves/CU, co-residency guaranteed (no deadlock mode).
// Tasks: wav0 S=32 (16384 tasks, 2/wave exact), wav1/2 S=16 (8192, 1/wave).
// Hierarchical barrier: 64 groups x 32 blocks, single-broadcaster release,
// s_sleep(8) polls (release lines are read-only until the one store).

constexpr int NBLK   = 2048;
constexpr int TPB    = 256;
constexpr int NWAVES = NBLK * (TPB / 64);   // 8192
constexpr int NGRP   = 64;
constexpr int GRP    = NBLK / NGRP;         // 32

// barrier layout (ints, 128B stride/slot): grpArr[g]@g*32, grpRel[g]@(64+g)*32,
// gArr@128*32. memset 20KB covers all.
// ---------------------------------------------------------------------------
__device__ __forceinline__ void gridbar(int* __restrict__ bar, int k)
{
    __syncthreads();
    if (threadIdx.x == 0) {
        const int g = blockIdx.x >> 5;          // group of 32 blocks
        int* grpArr = bar + g * 32;
        int* grpRel = bar + (NGRP + g) * 32;
        int* gArr   = bar + 2 * NGRP * 32;

        __threadfence();  // release my phase's global writes
        int old = __hip_atomic_fetch_add(grpArr, 1, __ATOMIC_RELAXED,
                                         __HIP_MEMORY_SCOPE_AGENT);
        if (old == k * GRP - 1) {               // last arriver in group
            __threadfence();
            int o2 = __hip_atomic_fetch_add(gArr, 1, __ATOMIC_RELAXED,
                                            __HIP_MEMORY_SCOPE_AGENT);
            if (o2 == k * NGRP - 1) {           // last group: broadcast release
                __threadfence();
#pragma unroll
                for (int j = 0; j < NGRP; ++j)
                    __hip_atomic_store(bar + (NGRP + j) * 32, k,
                                       __ATOMIC_RELAXED, __HIP_MEMORY_SCOPE_AGENT);
            }
        }
        while (__hip_atomic_load(grpRel, __ATOMIC_RELAXED,
                                 __HIP_MEMORY_SCOPE_AGENT) < k)
            __builtin_amdgcn_s_sleep(8);        // ~0.2us wake, read-only line
        __threadfence();  // acquire side
    }
    __syncthreads();
}

// ---------------------------------------------------------------------------
// Wavelet layer phase. Task = (o, si); wave gw does TPW consecutive tasks.
// Per-wave LDS prep slab: float4 {inv, -t*inv, w, pad} per i. Math identical
// to the verified versions; only the task decomposition (S) changed.
// ---------------------------------------------------------------------------
template<int KINL, int S, int TPW>
__device__ __forceinline__ void wav_phase(const float* __restrict__ xin,
        const float* __restrict__ w, const float* __restrict__ t,
        const float* __restrict__ s, float* __restrict__ part,
        float4* __restrict__ myPrep, int lane, int gw)
{
    constexpr int RANGE = KINL / S;      // i-values per task (192 or 32)
    constexpr int STEPS = RANGE / 4;
    constexpr int PREPS = (RANGE + 63) / 64;

#pragma unroll
    for (int ti = 0; ti < TPW; ++ti) {
        const int tau = gw * TPW + ti;
        const int o = tau & 511, si = tau >> 9;
        const int ibase = si * RANGE;

        const float* __restrict__ wp = w + (size_t)o * KINL + ibase;
        const float* __restrict__ tp = t + (size_t)o * KINL + ibase;
        const float* __restrict__ sp = s + (size_t)o * KINL + ibase;

        // per-wave slab; within-wave DS ordering is in-order -> no sync
#pragma unroll
        for (int r = 0; r < PREPS; ++r) {
            int il = r * 64 + lane;
            if ((RANGE % 64 == 0) || il < RANGE) {
                float wv = wp[il], tv = tp[il], sv = sp[il];
                float sig = __builtin_amdgcn_rcpf(1.f + EXP2F(-sv * LOG2E));
                float inv = __builtin_amdgcn_rcpf(fmaf(9.99f, sig, 0.01000001f));
                myPrep[il] = make_float4(inv, -tv * inv, wv, 0.f);
            }
        }

        const int p = lane & 15, g = lane >> 4;
        const float2* __restrict__ xp =
            (const float2*)xin + (size_t)(ibase + g) * 16 + p;

        float acc0 = 0.f, acc1 = 0.f;
#pragma unroll 8
        for (int st = 0; st < STEPS; ++st) {
            float4 pr = myPrep[st * 4 + g];          // ds_read_b128, broadcast
            float2 xv = xp[(size_t)st * 64];         // 512B contiguous per wave
            float u0 = fmaf(xv.x, pr.x, pr.y);
            float u1 = fmaf(xv.y, pr.x, pr.y);
            float q0 = u0 * u0, q1 = u1 * u1;
            float e0 = EXP2F(q0 * NHALF_LOG2E);
            float e1 = EXP2F(q1 * NHALF_LOG2E);
            float pw0 = fmaf(-pr.z, q0, pr.z);
            float pw1 = fmaf(-pr.z, q1, pr.z);
            acc0 = fmaf(pw0, e0, acc0);
            acc1 = fmaf(pw1, e1, acc1);
        }

        acc0 += __shfl_down(acc0, 32); acc0 += __shfl_down(acc0, 16);
        acc1 += __shfl_down(acc1, 32); acc1 += __shfl_down(acc1, 16);
        if (lane < 16) {
            float2* pp = (float2*)(part + (size_t)si * 16384 + o * 32) + p;
            *pp = make_float2(acc0, acc1);
        }
    }
}

// ---------------------------------------------------------------------------
// silu + LayerNorm: block b (<32) = batch row, 256 threads, each owns
// o = tid and o = tid+256. Writes hT[o][b].
// ---------------------------------------------------------------------------
template<int S>
__device__ __forceinline__ void ln_phase(const float* __restrict__ part,
        const float* __restrict__ gam, const float* __restrict__ bet,
        float* __restrict__ hT, float* __restrict__ r1, float* __restrict__ r2)
{
    if (blockIdx.x < 32) {
        const int b = blockIdx.x, tid = threadIdx.x;
        float a[2];
#pragma unroll
        for (int j = 0; j < 2; ++j) {
            const int o = tid + j * 256;
            float v = 0.f;
#pragma unroll
            for (int si = 0; si < S; ++si)
                v += part[(size_t)si * 16384 + o * 32 + b];
            a[j] = v * __builtin_amdgcn_rcpf(1.f + EXP2F(-v * LOG2E));  // silu
        }
        float s1 = a[0] + a[1], s2 = a[0] * a[0] + a[1] * a[1];
#pragma unroll
        for (int off = 32; off; off >>= 1) {
            s1 += __shfl_xor(s1, off);
            s2 += __shfl_xor(s2, off);
        }
        const int lane = tid & 63, wid = tid >> 6;
        if (lane == 0) { r1[wid] = s1; r2[wid] = s2; }
        __syncthreads();
        float t1 = 0.f, t2 = 0.f;
#pragma unroll
        for (int k = 0; k < 4; ++k) { t1 += r1[k]; t2 += r2[k]; }
        float m   = t1 * (1.f / 512.f);
        float var = t2 * (1.f / 512.f) - m * m;
        float r   = __builtin_amdgcn_rsqf(var + LN_EPS);
#pragma unroll
        for (int j = 0; j < 2; ++j) {
            const int o = tid + j * 256;
            hT[o * 32 + b] = (a[j] - m) * r * gam[o] + bet[o];
        }
    }
}

// ---------------------------------------------------------------------------
// Final: silu + LN + classifier. Block b (<32) = batch row, 2 o's per thread.
// ---------------------------------------------------------------------------
template<int S>
__device__ __forceinline__ void cls_phase(const float* __restrict__ part,
        const float* __restrict__ gam, const float* __restrict__ bet,
        const float* __restrict__ cw, const float* __restrict__ cb,
        float* __restrict__ out, float* __restrict__ r1, float* __restrict__ r2,
        float (* __restrict__ cr)[4])
{
    if (blockIdx.x < 32) {
        const int b = blockIdx.x, tid = threadIdx.x;
        float a[2];
#pragma unroll
        for (int j = 0; j < 2; ++j) {
            const int o = tid + j * 256;
            float v = 0.f;
#pragma unroll
            for (int si = 0; si < S; ++si)
                v += part[(size_t)si * 16384 + o * 32 + b];
            a[j] = v * __builtin_amdgcn_rcpf(1.f + EXP2F(-v * LOG2E));
        }
        float s1 = a[0] + a[1], s2 = a[0] * a[0] + a[1] * a[1];
#pragma unroll
        for (int off = 32; off; off >>= 1) {
            s1 += __shfl_xor(s1, off);
            s2 += __shfl_xor(s2, off);
        }
        const int lane = tid & 63, wid = tid >> 6;
        if (lane == 0) { r1[wid] = s1; r2[wid] = s2; }
        __syncthreads();
        float t1 = 0.f, t2 = 0.f;
#pragma unroll
        for (int k = 0; k < 4; ++k) { t1 += r1[k]; t2 += r2[k]; }
        float m   = t1 * (1.f / 512.f);
        float var = t2 * (1.f / 512.f) - m * m;
        float r   = __builtin_amdgcn_rsqf(var + LN_EPS);
        float hl0 = (a[0] - m) * r * gam[tid] + bet[tid];
        float hl1 = (a[1] - m) * r * gam[tid + 256] + bet[tid + 256];

#pragma unroll
        for (int c = 0; c < 5; ++c) {
            float pv = hl0 * cw[c * 512 + tid] + hl1 * cw[c * 512 + tid + 256];
#pragma unroll
            for (int off = 32; off; off >>= 1) pv += __shfl_xor(pv, off);
            if (lane == 0) cr[c][wid] = pv;
        }
        __syncthreads();
        if (tid < 5) {
            float sum = 0.f;
#pragma unroll
            for (int k = 0; k < 4; ++k) sum += cr[tid][k];
            out[b * 5 + tid] = sum + cb[tid];
        }
    }
}

// ---------------------------------------------------------------------------
__global__ __launch_bounds__(TPB, 8)
void megakernel(const float* __restrict__ x,
                const float* __restrict__ w0, const float* __restrict__ t0,
                const float* __restrict__ s0, const float* __restrict__ g0,
                const float* __restrict__ b0,
                const float* __restrict__ w1, const float* __restrict__ t1,
                const float* __restrict__ s1, const float* __restrict__ g1,
                const float* __restrict__ b1,
                const float* __restrict__ w2, const float* __restrict__ t2,
                const float* __restrict__ s2, const float* __restrict__ g2,
                const float* __restrict__ b2,
                const float* __restrict__ cw, const float* __restrict__ cb,
                float* __restrict__ out,
                float* __restrict__ xT, float* __restrict__ part,
                float* __restrict__ hT, int* __restrict__ bar)
{
    __shared__ float4 prep[4][192];          // 12 KiB: per-wave prep slab
    __shared__ float r1[4], r2[4], cr[5][4]; // LN/cls reduction scratch

    const int wave = threadIdx.x >> 6, lane = threadIdx.x & 63;
    const int gw = blockIdx.x * (TPB / 64) + wave;
    float4* myPrep = prep[wave];

    // phase 0: transpose x (32 x 6144) -> xT (6144 x 32)
    {
        int idx = blockIdx.x * TPB + threadIdx.x;
        if (idx < 6144 * 32)
            xT[idx] = x[(idx & 31) * 6144 + (idx >> 5)];
    }
    gridbar(bar, 1);

    wav_phase<6144, 32, 2>(xT, w0, t0, s0, part, myPrep, lane, gw);  // 16384 tasks
    gridbar(bar, 2);
    ln_phase<32>(part, g0, b0, hT, r1, r2);
    gridbar(bar, 3);

    wav_phase<512, 16, 1>(hT, w1, t1, s1, part, myPrep, lane, gw);   // 8192 tasks
    gridbar(bar, 4);
    ln_phase<16>(part, g1, b1, hT, r1, r2);
    gridbar(bar, 5);

    wav_phase<512, 16, 1>(hT, w2, t2, s2, part, myPrep, lane, gw);
    gridbar(bar, 6);
    cls_phase<16>(part, g2, b2, cw, cb, out, r1, r2, cr);
}

extern "C" void kernel_launch(void* const* d_in, const int* in_sizes, int n_in,
                              void* d_out, int out_size, void* d_ws, size_t ws_size,
                              hipStream_t stream)
{
    const float* x  = (const float*)d_in[0];
    const float* w0 = (const float*)d_in[1];
    const float* t0 = (const float*)d_in[2];
    const float* s0 = (const float*)d_in[3];
    const float* g0 = (const float*)d_in[4];
    const float* b0 = (const float*)d_in[5];
    const float* w1 = (const float*)d_in[6];
    const float* t1 = (const float*)d_in[7];
    const float* s1 = (const float*)d_in[8];
    const float* g1 = (const float*)d_in[9];
    const float* b1 = (const float*)d_in[10];
    const float* w2 = (const float*)d_in[11];
    const float* t2 = (const float*)d_in[12];
    const float* s2 = (const float*)d_in[13];
    const float* g2 = (const float*)d_in[14];
    const float* b2 = (const float*)d_in[15];
    const float* cw = (const float*)d_in[16];
    const float* cb = (const float*)d_in[17];
    float* out = (float*)d_out;

    // ws layout (floats): xT 196608 | part 32*16384 | hT 16384 | barrier (20KB)
    float* xT   = (float*)d_ws;
    float* part = xT + 196608;
    float* hT   = part + 32 * 16384;
    int*   bar  = (int*)(hT + 16384);        // 128B-strided slots

    hipMemsetAsync(bar, 0, 20480, stream);   // capture-safe barrier reset

    void* args[] = { (void*)&x,
                     (void*)&w0, (void*)&t0, (void*)&s0, (void*)&g0, (void*)&b0,
                     (void*)&w1, (void*)&t1, (void*)&s1, (void*)&g1, (void*)&b1,
                     (void*)&w2, (void*)&t2, (void*)&s2, (void*)&g2, (void*)&b2,
                     (void*)&cw, (void*)&cb, (void*)&out,
                     (void*)&xT, (void*)&part, (void*)&hT, (void*)&bar };

    hipLaunchKernel((const void*)megakernel, dim3(NBLK), dim3(TPB),
                    args, 0, stream);
}

// Round 6
// 190.614 us; speedup vs baseline: 3.5896x; 3.5896x over previous
//
#include <hip/hip_runtime.h>

#define LN_EPS 1e-5f
#define LOG2E 1.44269504f
#define NHALF_LOG2E (-0.72134752f)

#if __has_builtin(__builtin_amdgcn_exp2f)
#define EXP2F(x) __builtin_amdgcn_exp2f(x)
#else
#define EXP2F(x) __expf((x) * 0.69314718f)
#endif

// Megakernel: wav0(LDS-x) -> ln0 -> wav1 -> ln1 -> wav2 -> ln2+cls. 5 barriers.
// Round 2-5 differential: barrier cost ~ (#block-leaders executing
// __threadfence) x ~0.45us (agent fences = buffer_wbl2/inv = whole-L2
// writeback/invalidate, serialized per XCD). 256 leaders x 6 bar ~ 100us of
// R4's 136; 2048 leaders ~ 580 of R5's 617. Fix: NO fences anywhere.
//  - part/hT accessed ONLY via system-scope relaxed atomics (sc0 sc1,
//    cache-bypass -> always coherent at L3; total traffic ~40MB, cheap).
//  - gridbar: all-thread s_waitcnt vmcnt(0) (drains system stores to the
//    coherence point) + relaxed agent atomics. Zero cache maintenance.
//  - xT (the one buffer that needed L2 caching: 402MB re-read) eliminated:
//    wav0 stages its si-slab of x into LDS (26KB, pad-34 rows, <=2-way
//    conflicts) -> transpose phase + its barrier gone.
// Grid = 256 blocks x 512 thr (R3/R4 proven shape), ~51KB LDS < 64KB static.

constexpr int NBLK   = 256;
constexpr int TPB    = 512;
constexpr int NWAVES = NBLK * (TPB / 64);   // 2048
constexpr int NGRP   = 8;
constexpr int GRP    = NBLK / NGRP;         // 32
constexpr int PADX   = 34;                  // x-slab row stride (even, 8B align)

// ---------------------------------------------------------------------------
__device__ __forceinline__ float sysld(const float* p)
{
    return __hip_atomic_load((const float*)p, __ATOMIC_RELAXED,
                             __HIP_MEMORY_SCOPE_SYSTEM);
}
__device__ __forceinline__ void sysst(float* p, float v)
{
    __hip_atomic_store(p, v, __ATOMIC_RELAXED, __HIP_MEMORY_SCOPE_SYSTEM);
}

// barrier layout (ints, 128B stride): grpArr[g]@g*32, grpRel[g]@(8+g)*32,
// gArr@16*32. Fence-free: data already at coherence point via vmcnt drain.
// ---------------------------------------------------------------------------
__device__ __forceinline__ void gridbar(int* __restrict__ bar, int k)
{
    asm volatile("s_waitcnt vmcnt(0)" ::: "memory");  // my system-stores @ L3
    __syncthreads();                                  // whole block drained
    if (threadIdx.x == 0) {
        const int g = blockIdx.x >> 5;
        int* grpArr = bar + g * 32;
        int* grpRel = bar + (NGRP + g) * 32;
        int* gArr   = bar + 2 * NGRP * 32;

        int old = __hip_atomic_fetch_add(grpArr, 1, __ATOMIC_RELAXED,
                                         __HIP_MEMORY_SCOPE_AGENT);
        if (old == k * GRP - 1) {               // last arriver in group
            int o2 = __hip_atomic_fetch_add(gArr, 1, __ATOMIC_RELAXED,
                                            __HIP_MEMORY_SCOPE_AGENT);
            if (o2 == k * NGRP - 1) {           // last group: broadcast release
#pragma unroll
                for (int j = 0; j < NGRP; ++j)
                    __hip_atomic_store(bar + (NGRP + j) * 32, k,
                                       __ATOMIC_RELAXED, __HIP_MEMORY_SCOPE_AGENT);
            }
        }
        while (__hip_atomic_load(grpRel, __ATOMIC_RELAXED,
                                 __HIP_MEMORY_SCOPE_AGENT) < k)
            __builtin_amdgcn_s_sleep(16);       // ~0.43us wake
    }
    __syncthreads();
}

// ---------------------------------------------------------------------------
// wav0: KIN=6144, S=32 (RANGE=192). Block bid: si = bid>>3, o-range =
// (bid&7)*64 .. +64. x si-slab staged+transposed into LDS once per block.
// Wave w does 8 tasks: o = obase + w*8 + t. Math identical to verified code.
// ---------------------------------------------------------------------------
__device__ __forceinline__ void wav0_phase(const float* __restrict__ x,
        const float* __restrict__ w, const float* __restrict__ t,
        const float* __restrict__ s, float* __restrict__ part,
        float4* __restrict__ myPrep, float* __restrict__ xs,
        int lane, int wave)
{
    constexpr int RANGE = 192, STEPS = RANGE / 4, TPW = 8;
    const int si    = blockIdx.x >> 3;
    const int obase = (blockIdx.x & 7) * 64;
    const int ibase = si * RANGE;

    // stage x[0..31][ibase..ibase+192) -> xs[i][b] (pad-34 rows)
    for (int b = wave; b < 32; b += 8)
        for (int i2 = lane; i2 < RANGE; i2 += 64)
            xs[i2 * PADX + b] = x[b * 6144 + ibase + i2];
    __syncthreads();

    const int p = lane & 15, g = lane >> 4;

#pragma unroll
    for (int ti = 0; ti < TPW; ++ti) {
        const int o = obase + wave * 8 + ti;
        const float* __restrict__ wp = w + (size_t)o * 6144 + ibase;
        const float* __restrict__ tp = t + (size_t)o * 6144 + ibase;
        const float* __restrict__ sp = s + (size_t)o * 6144 + ibase;

        // per-wave prep slab {inv, -t*inv, w, pad}; in-order DS -> no sync
#pragma unroll
        for (int r = 0; r < RANGE / 64; ++r) {
            int il = r * 64 + lane;
            float wv = wp[il], tv = tp[il], sv = sp[il];
            float sig = __builtin_amdgcn_rcpf(1.f + EXP2F(-sv * LOG2E));
            float inv = __builtin_amdgcn_rcpf(fmaf(9.99f, sig, 0.01000001f));
            myPrep[il] = make_float4(inv, -tv * inv, wv, 0.f);
        }

        float acc0 = 0.f, acc1 = 0.f;
#pragma unroll 8
        for (int st = 0; st < STEPS; ++st) {
            float4 pr = myPrep[st * 4 + g];
            float2 xv = *(const float2*)&xs[(st * 4 + g) * PADX + 2 * p];
            float u0 = fmaf(xv.x, pr.x, pr.y);
            float u1 = fmaf(xv.y, pr.x, pr.y);
            float q0 = u0 * u0, q1 = u1 * u1;
            float e0 = EXP2F(q0 * NHALF_LOG2E);
            float e1 = EXP2F(q1 * NHALF_LOG2E);
            float pw0 = fmaf(-pr.z, q0, pr.z);
            float pw1 = fmaf(-pr.z, q1, pr.z);
            acc0 = fmaf(pw0, e0, acc0);
            acc1 = fmaf(pw1, e1, acc1);
        }

        acc0 += __shfl_down(acc0, 32); acc0 += __shfl_down(acc0, 16);
        acc1 += __shfl_down(acc1, 32); acc1 += __shfl_down(acc1, 16);
        if (lane < 16) {
            float* pp = part + (size_t)si * 16384 + o * 32 + 2 * p;
            sysst(pp, acc0); sysst(pp + 1, acc1);
        }
    }
}

// ---------------------------------------------------------------------------
// wav1/2: KIN=512, S=8 (RANGE=64), TPW=2. Input h read via system loads
// (L3-coherent, ~33MB total). Math identical to verified code.
// ---------------------------------------------------------------------------
__device__ __forceinline__ void wav12_phase(const float* __restrict__ hin,
        const float* __restrict__ w, const float* __restrict__ t,
        const float* __restrict__ s, float* __restrict__ part,
        float4* __restrict__ myPrep, int lane, int gw)
{
    constexpr int RANGE = 64, STEPS = RANGE / 4, TPW = 2;
    const int p = lane & 15, g = lane >> 4;

#pragma unroll
    for (int ti = 0; ti < TPW; ++ti) {
        const int tau = gw * TPW + ti;
        const int o = tau & 511, si = tau >> 9;
        const int ibase = si * RANGE;

        const float* __restrict__ wp = w + (size_t)o * 512 + ibase;
        const float* __restrict__ tp = t + (size_t)o * 512 + ibase;
        const float* __restrict__ sp = s + (size_t)o * 512 + ibase;

        {
            int il = lane;      // RANGE == 64: one round
            float wv = wp[il], tv = tp[il], sv = sp[il];
            float sig = __builtin_amdgcn_rcpf(1.f + EXP2F(-sv * LOG2E));
            float inv = __builtin_amdgcn_rcpf(fmaf(9.99f, sig, 0.01000001f));
            myPrep[il] = make_float4(inv, -tv * inv, wv, 0.f);
        }

        const float* __restrict__ hp = hin + (size_t)(ibase + g) * 32 + 2 * p;

        float acc0 = 0.f, acc1 = 0.f;
#pragma unroll 8
        for (int st = 0; st < STEPS; ++st) {
            float4 pr = myPrep[st * 4 + g];
            float x0 = sysld(hp + (size_t)st * 128);
            float x1 = sysld(hp + (size_t)st * 128 + 1);
            float u0 = fmaf(x0, pr.x, pr.y);
            float u1 = fmaf(x1, pr.x, pr.y);
            float q0 = u0 * u0, q1 = u1 * u1;
            float e0 = EXP2F(q0 * NHALF_LOG2E);
            float e1 = EXP2F(q1 * NHALF_LOG2E);
            float pw0 = fmaf(-pr.z, q0, pr.z);
            float pw1 = fmaf(-pr.z, q1, pr.z);
            acc0 = fmaf(pw0, e0, acc0);
            acc1 = fmaf(pw1, e1, acc1);
        }

        acc0 += __shfl_down(acc0, 32); acc0 += __shfl_down(acc0, 16);
        acc1 += __shfl_down(acc1, 32); acc1 += __shfl_down(acc1, 16);
        if (lane < 16) {
            float* pp = part + (size_t)si * 16384 + o * 32 + 2 * p;
            sysst(pp, acc0); sysst(pp + 1, acc1);
        }
    }
}

// ---------------------------------------------------------------------------
// silu + LayerNorm: block b (<32) = batch row, tid = o. Writes hT[o][b].
// ---------------------------------------------------------------------------
template<int S>
__device__ __forceinline__ void ln_phase(const float* __restrict__ part,
        const float* __restrict__ gam, const float* __restrict__ bet,
        float* __restrict__ hT, float* __restrict__ r1, float* __restrict__ r2)
{
    if (blockIdx.x < 32) {
        const int b = blockIdx.x, tid = threadIdx.x;
        float v = 0.f;
#pragma unroll
        for (int si = 0; si < S; ++si)
            v += sysld(part + (size_t)si * 16384 + tid * 32 + b);
        float a = v * __builtin_amdgcn_rcpf(1.f + EXP2F(-v * LOG2E));  // silu

        float s1 = a, s2 = a * a;
#pragma unroll
        for (int off = 32; off; off >>= 1) {
            s1 += __shfl_down(s1, off);
            s2 += __shfl_down(s2, off);
        }
        const int lane = tid & 63, wid = tid >> 6;
        if (lane == 0) { r1[wid] = s1; r2[wid] = s2; }
        __syncthreads();
        float t1 = 0.f, t2 = 0.f;
#pragma unroll
        for (int k = 0; k < 8; ++k) { t1 += r1[k]; t2 += r2[k]; }
        float m   = t1 * (1.f / 512.f);
        float var = t2 * (1.f / 512.f) - m * m;
        float r   = __builtin_amdgcn_rsqf(var + LN_EPS);
        sysst(hT + tid * 32 + b, (a - m) * r * gam[tid] + bet[tid]);
    }
}

// ---------------------------------------------------------------------------
// Final: silu + LN + classifier, block b (<32) = batch row, tid = o.
// ---------------------------------------------------------------------------
template<int S>
__device__ __forceinline__ void cls_phase(const float* __restrict__ part,
        const float* __restrict__ gam, const float* __restrict__ bet,
        const float* __restrict__ cw, const float* __restrict__ cb,
        float* __restrict__ out, float* __restrict__ r1, float* __restrict__ r2,
        float (* __restrict__ cr)[8])
{
    if (blockIdx.x < 32) {
        const int b = blockIdx.x, tid = threadIdx.x;
        float v = 0.f;
#pragma unroll
        for (int si = 0; si < S; ++si)
            v += sysld(part + (size_t)si * 16384 + tid * 32 + b);
        float a = v * __builtin_amdgcn_rcpf(1.f + EXP2F(-v * LOG2E));

        float s1 = a, s2 = a * a;
#pragma unroll
        for (int off = 32; off; off >>= 1) {
            s1 += __shfl_down(s1, off);
            s2 += __shfl_down(s2, off);
        }
        const int lane = tid & 63, wid = tid >> 6;
        if (lane == 0) { r1[wid] = s1; r2[wid] = s2; }
        __syncthreads();
        float t1 = 0.f, t2 = 0.f;
#pragma unroll
        for (int k = 0; k < 8; ++k) { t1 += r1[k]; t2 += r2[k]; }
        float m   = t1 * (1.f / 512.f);
        float var = t2 * (1.f / 512.f) - m * m;
        float r   = __builtin_amdgcn_rsqf(var + LN_EPS);
        float hl  = (a - m) * r * gam[tid] + bet[tid];

#pragma unroll
        for (int c = 0; c < 5; ++c) {
            float pv = hl * cw[c * 512 + tid];
#pragma unroll
            for (int off = 32; off; off >>= 1) pv += __shfl_down(pv, off);
            if (lane == 0) cr[c][wid] = pv;
        }
        __syncthreads();
        if (tid < 5) {
            float sum = 0.f;
#pragma unroll
            for (int k = 0; k < 8; ++k) sum += cr[tid][k];
            out[b * 5 + tid] = sum + cb[tid];
        }
    }
}

// ---------------------------------------------------------------------------
__global__ __launch_bounds__(TPB)
void megakernel(const float* __restrict__ x,
                const float* __restrict__ w0, const float* __restrict__ t0,
                const float* __restrict__ s0, const float* __restrict__ g0,
                const float* __restrict__ b0,
                const float* __restrict__ w1, const float* __restrict__ t1,
                const float* __restrict__ s1, const float* __restrict__ g1,
                const float* __restrict__ b1,
                const float* __restrict__ w2, const float* __restrict__ t2,
                const float* __restrict__ s2, const float* __restrict__ g2,
                const float* __restrict__ b2,
                const float* __restrict__ cw, const float* __restrict__ cb,
                float* __restrict__ out,
                float* __restrict__ part, float* __restrict__ hT,
                int* __restrict__ bar)
{
    __shared__ float4 prep[8][192];             // 24.6 KiB per-wave prep slabs
    __shared__ float  xs[192 * PADX];           // 26.1 KiB x si-slab [i][b]
    __shared__ float  r1[8], r2[8], cr[5][8];   // LN/cls reduction scratch

    const int wave = threadIdx.x >> 6, lane = threadIdx.x & 63;
    const int gw = blockIdx.x * (TPB / 64) + wave;
    float4* myPrep = prep[wave];

    wav0_phase(x, w0, t0, s0, part, myPrep, xs, lane, wave);  // 16384 tasks
    gridbar(bar, 1);
    ln_phase<32>(part, g0, b0, hT, r1, r2);
    gridbar(bar, 2);

    wav12_phase(hT, w1, t1, s1, part, myPrep, lane, gw);      // 4096 tasks
    gridbar(bar, 3);
    ln_phase<8>(part, g1, b1, hT, r1, r2);
    gridbar(bar, 4);

    wav12_phase(hT, w2, t2, s2, part, myPrep, lane, gw);
    gridbar(bar, 5);
    cls_phase<8>(part, g2, b2, cw, cb, out, r1, r2, cr);
}

extern "C" void kernel_launch(void* const* d_in, const int* in_sizes, int n_in,
                              void* d_out, int out_size, void* d_ws, size_t ws_size,
                              hipStream_t stream)
{
    const float* x  = (const float*)d_in[0];
    const float* w0 = (const float*)d_in[1];
    const float* t0 = (const float*)d_in[2];
    const float* s0 = (const float*)d_in[3];
    const float* g0 = (const float*)d_in[4];
    const float* b0 = (const float*)d_in[5];
    const float* w1 = (const float*)d_in[6];
    const float* t1 = (const float*)d_in[7];
    const float* s1 = (const float*)d_in[8];
    const float* g1 = (const float*)d_in[9];
    const float* b1 = (const float*)d_in[10];
    const float* w2 = (const float*)d_in[11];
    const float* t2 = (const float*)d_in[12];
    const float* s2 = (const float*)d_in[13];
    const float* g2 = (const float*)d_in[14];
    const float* b2 = (const float*)d_in[15];
    const float* cw = (const float*)d_in[16];
    const float* cb = (const float*)d_in[17];
    float* out = (float*)d_out;

    // ws layout (floats): part 32*16384 (2MB) | hT 16384 | barrier (4KB)
    float* part = (float*)d_ws;
    float* hT   = part + 32 * 16384;
    int*   bar  = (int*)(hT + 16384);

    hipMemsetAsync(bar, 0, 4096, stream);    // capture-safe barrier reset

    void* args[] = { (void*)&x,
                     (void*)&w0, (void*)&t0, (void*)&s0, (void*)&g0, (void*)&b0,
                     (void*)&w1, (void*)&t1, (void*)&s1, (void*)&g1, (void*)&b1,
                     (void*)&w2, (void*)&t2, (void*)&s2, (void*)&g2, (void*)&b2,
                     (void*)&cw, (void*)&cb, (void*)&out,
                     (void*)&part, (void*)&hT, (void*)&bar };

    hipLaunchKernel((const void*)megakernel, dim3(NBLK), dim3(TPB),
                    args, 0, stream);
}

// Round 7
// 179.170 us; speedup vs baseline: 3.8189x; 1.0639x over previous
//
#include <hip/hip_runtime.h>

#define LN_EPS 1e-5f
#define LOG2E 1.44269504f
#define NHALF_LOG2E (-0.72134752f)

#if __has_builtin(__builtin_amdgcn_exp2f)
#define EXP2F(x) __builtin_amdgcn_exp2f(x)
#else
#define EXP2F(x) __expf((x) * 0.69314718f)
#endif

// Megakernel: wav0(LDS-x) -> ln0 -> wav1 -> ln1 -> wav2 -> ln2+cls. 5 barriers.
// R6 lessons: fence-free barrier works (136->91us); residual ~72us is memory
// latency at 1 block/CU (2 waves/SIMD). This round: occupancy + prefetch.
//  - 512 blocks x 512 thr = 2 blocks/CU (4 waves/SIMD). LDS 51KB -> 3/CU
//    capacity; __launch_bounds__(512,4) caps VGPR<=128 -> all 512 blocks
//    co-resident guaranteed (no barrier deadlock mode).
//  - wav0 prefetches next task's w/t/s rows into regs during current task's
//    inner loop; wav1/2 prep rows prefetched BEFORE the preceding barrier
//    (loads complete during barrier wait + LN phase).
//  - b64 system-scope loads/stores (sysld2/sysst2) halve cache-bypass ops.
// part/hT accessed ONLY via system-scope relaxed atomics (coherent at L3,
// no fences needed); gridbar = vmcnt-drain + relaxed agent atomics only.

constexpr int NBLK   = 512;
constexpr int TPB    = 512;
constexpr int NWAVES = NBLK * (TPB / 64);   // 4096
constexpr int NGRP   = 16;
constexpr int GRP    = NBLK / NGRP;         // 32
constexpr int PADX   = 34;                  // x-slab row stride (even, 8B align)

// ---------------------------------------------------------------------------
__device__ __forceinline__ float sysld(const float* p)
{
    return __hip_atomic_load(p, __ATOMIC_RELAXED, __HIP_MEMORY_SCOPE_SYSTEM);
}
__device__ __forceinline__ void sysst(float* p, float v)
{
    __hip_atomic_store(p, v, __ATOMIC_RELAXED, __HIP_MEMORY_SCOPE_SYSTEM);
}
__device__ __forceinline__ float2 sysld2(const float* p)
{
    unsigned long long v = __hip_atomic_load((const unsigned long long*)p,
        __ATOMIC_RELAXED, __HIP_MEMORY_SCOPE_SYSTEM);
    union { unsigned long long u; float2 f; } c; c.u = v; return c.f;
}
__device__ __forceinline__ void sysst2(float* p, float a, float b)
{
    union { unsigned long long u; float2 f; } c; c.f = make_float2(a, b);
    __hip_atomic_store((unsigned long long*)p, c.u, __ATOMIC_RELAXED,
                       __HIP_MEMORY_SCOPE_SYSTEM);
}

// barrier layout (ints, 128B stride): grpArr[g]@g*32, grpRel[g]@(NGRP+g)*32,
// gArr@2*NGRP*32. Fence-free: data is at the coherence point via vmcnt drain.
// ---------------------------------------------------------------------------
__device__ __forceinline__ void gridbar(int* __restrict__ bar, int k)
{
    asm volatile("s_waitcnt vmcnt(0)" ::: "memory");  // my system-stores @ L3
    __syncthreads();                                  // whole block drained
    if (threadIdx.x == 0) {
        const int g = blockIdx.x >> 5;
        int* grpArr = bar + g * 32;
        int* grpRel = bar + (NGRP + g) * 32;
        int* gArr   = bar + 2 * NGRP * 32;

        int old = __hip_atomic_fetch_add(grpArr, 1, __ATOMIC_RELAXED,
                                         __HIP_MEMORY_SCOPE_AGENT);
        if (old == k * GRP - 1) {               // last arriver in group
            int o2 = __hip_atomic_fetch_add(gArr, 1, __ATOMIC_RELAXED,
                                            __HIP_MEMORY_SCOPE_AGENT);
            if (o2 == k * NGRP - 1) {           // last group: broadcast release
#pragma unroll
                for (int j = 0; j < NGRP; ++j)
                    __hip_atomic_store(bar + (NGRP + j) * 32, k,
                                       __ATOMIC_RELAXED, __HIP_MEMORY_SCOPE_AGENT);
            }
        }
        while (__hip_atomic_load(grpRel, __ATOMIC_RELAXED,
                                 __HIP_MEMORY_SCOPE_AGENT) < k)
            __builtin_amdgcn_s_sleep(8);        // ~0.2us wake, read-only line
    }
    __syncthreads();
}

// ---------------------------------------------------------------------------
// wav0: KIN=6144, S=32 (RANGE=192). Block bid: si = bid>>4, o-range =
// (bid&15)*32 .. +32. x si-slab staged+transposed into LDS once per block.
// Wave w does TPW=4 tasks: o = obase + w*4 + ti. Next task's w/t/s rows are
// prefetched into registers during the current inner loop.
// ---------------------------------------------------------------------------
__device__ __forceinline__ void wav0_phase(const float* __restrict__ x,
        const float* __restrict__ w, const float* __restrict__ t,
        const float* __restrict__ s, float* __restrict__ part,
        float4* __restrict__ myPrep, float* __restrict__ xs,
        int lane, int wave)
{
    constexpr int RANGE = 192, STEPS = RANGE / 4, TPW = 4;
    const int si    = blockIdx.x >> 4;
    const int obase = (blockIdx.x & 15) * 32;
    const int ibase = si * RANGE;

    // stage x[0..31][ibase..ibase+192) -> xs[i][b] (pad-34 rows)
    for (int b = wave; b < 32; b += 8)
        for (int i2 = lane; i2 < RANGE; i2 += 64)
            xs[i2 * PADX + b] = x[b * 6144 + ibase + i2];
    __syncthreads();

    const int p = lane & 15, g = lane >> 4;
    const int o0 = obase + wave * TPW;
    const float* __restrict__ wp = w + (size_t)o0 * 6144 + ibase;
    const float* __restrict__ tp = t + (size_t)o0 * 6144 + ibase;
    const float* __restrict__ sp = s + (size_t)o0 * 6144 + ibase;

    float fw[3], ft[3], fs[3];
#pragma unroll
    for (int r = 0; r < 3; ++r) {
        int il = r * 64 + lane;
        fw[r] = wp[il]; ft[r] = tp[il]; fs[r] = sp[il];
    }

#pragma unroll
    for (int ti = 0; ti < TPW; ++ti) {
        // build prep slab from the prefetched registers
#pragma unroll
        for (int r = 0; r < 3; ++r) {
            int il = r * 64 + lane;
            float sig = __builtin_amdgcn_rcpf(1.f + EXP2F(-fs[r] * LOG2E));
            float inv = __builtin_amdgcn_rcpf(fmaf(9.99f, sig, 0.01000001f));
            myPrep[il] = make_float4(inv, -ft[r] * inv, fw[r], 0.f);
        }
        // issue next task's param loads (hidden under this task's inner loop)
        if (ti + 1 < TPW) {
            const float* wpn = wp + (size_t)(ti + 1) * 6144;
            const float* tpn = tp + (size_t)(ti + 1) * 6144;
            const float* spn = sp + (size_t)(ti + 1) * 6144;
#pragma unroll
            for (int r = 0; r < 3; ++r) {
                int il = r * 64 + lane;
                fw[r] = wpn[il]; ft[r] = tpn[il]; fs[r] = spn[il];
            }
        }

        float acc0 = 0.f, acc1 = 0.f;
#pragma unroll 8
        for (int st = 0; st < STEPS; ++st) {
            float4 pr = myPrep[st * 4 + g];
            float2 xv = *(const float2*)&xs[(st * 4 + g) * PADX + 2 * p];
            float u0 = fmaf(xv.x, pr.x, pr.y);
            float u1 = fmaf(xv.y, pr.x, pr.y);
            float q0 = u0 * u0, q1 = u1 * u1;
            float e0 = EXP2F(q0 * NHALF_LOG2E);
            float e1 = EXP2F(q1 * NHALF_LOG2E);
            float pw0 = fmaf(-pr.z, q0, pr.z);
            float pw1 = fmaf(-pr.z, q1, pr.z);
            acc0 = fmaf(pw0, e0, acc0);
            acc1 = fmaf(pw1, e1, acc1);
        }

        acc0 += __shfl_down(acc0, 32); acc0 += __shfl_down(acc0, 16);
        acc1 += __shfl_down(acc1, 32); acc1 += __shfl_down(acc1, 16);
        if (lane < 16) {
            const int o = o0 + ti;
            sysst2(part + (size_t)si * 16384 + o * 32 + 2 * p, acc0, acc1);
        }
    }
}

// ---------------------------------------------------------------------------
// wav1/2: KIN=512, S=8 (RANGE=64), TPW=1: wave gw owns task gw.
// Prep params arrive prefetched in registers (loaded before the previous
// barrier). h read via b64 system loads (L3-coherent).
// ---------------------------------------------------------------------------
__device__ __forceinline__ void wav12_phase(const float* __restrict__ hin,
        float* __restrict__ part, float4* __restrict__ myPrep,
        int lane, int gw, float fw, float ft, float fs)
{
    constexpr int STEPS = 16;
    const int p = lane & 15, g = lane >> 4;
    const int o = gw & 511, si = gw >> 9;
    const int ibase = si * 64;

    {
        float sig = __builtin_amdgcn_rcpf(1.f + EXP2F(-fs * LOG2E));
        float inv = __builtin_amdgcn_rcpf(fmaf(9.99f, sig, 0.01000001f));
        myPrep[lane] = make_float4(inv, -ft * inv, fw, 0.f);
    }

    const float* __restrict__ hp = hin + (size_t)(ibase + g) * 32 + 2 * p;

    float acc0 = 0.f, acc1 = 0.f;
#pragma unroll 8
    for (int st = 0; st < STEPS; ++st) {
        float4 pr = myPrep[st * 4 + g];
        float2 xv = sysld2(hp + (size_t)st * 128);
        float u0 = fmaf(xv.x, pr.x, pr.y);
        float u1 = fmaf(xv.y, pr.x, pr.y);
        float q0 = u0 * u0, q1 = u1 * u1;
        float e0 = EXP2F(q0 * NHALF_LOG2E);
        float e1 = EXP2F(q1 * NHALF_LOG2E);
        float pw0 = fmaf(-pr.z, q0, pr.z);
        float pw1 = fmaf(-pr.z, q1, pr.z);
        acc0 = fmaf(pw0, e0, acc0);
        acc1 = fmaf(pw1, e1, acc1);
    }

    acc0 += __shfl_down(acc0, 32); acc0 += __shfl_down(acc0, 16);
    acc1 += __shfl_down(acc1, 32); acc1 += __shfl_down(acc1, 16);
    if (lane < 16)
        sysst2(part + (size_t)si * 16384 + o * 32 + 2 * p, acc0, acc1);
}

// ---------------------------------------------------------------------------
// silu + LayerNorm: block b (<32) = batch row, tid = o. Writes hT[o][b].
// ---------------------------------------------------------------------------
template<int S>
__device__ __forceinline__ void ln_phase(const float* __restrict__ part,
        const float* __restrict__ gam, const float* __restrict__ bet,
        float* __restrict__ hT, float* __restrict__ r1, float* __restrict__ r2)
{
    if (blockIdx.x < 32) {
        const int b = blockIdx.x, tid = threadIdx.x;
        float v = 0.f;
#pragma unroll
        for (int si = 0; si < S; ++si)
            v += sysld(part + (size_t)si * 16384 + tid * 32 + b);
        float a = v * __builtin_amdgcn_rcpf(1.f + EXP2F(-v * LOG2E));  // silu

        float s1 = a, s2 = a * a;
#pragma unroll
        for (int off = 32; off; off >>= 1) {
            s1 += __shfl_down(s1, off);
            s2 += __shfl_down(s2, off);
        }
        const int lane = tid & 63, wid = tid >> 6;
        if (lane == 0) { r1[wid] = s1; r2[wid] = s2; }
        __syncthreads();
        float t1 = 0.f, t2 = 0.f;
#pragma unroll
        for (int k = 0; k < 8; ++k) { t1 += r1[k]; t2 += r2[k]; }
        float m   = t1 * (1.f / 512.f);
        float var = t2 * (1.f / 512.f) - m * m;
        float r   = __builtin_amdgcn_rsqf(var + LN_EPS);
        sysst(hT + tid * 32 + b, (a - m) * r * gam[tid] + bet[tid]);
    }
}

// ---------------------------------------------------------------------------
// Final: silu + LN + classifier, block b (<32) = batch row, tid = o.
// ---------------------------------------------------------------------------
template<int S>
__device__ __forceinline__ void cls_phase(const float* __restrict__ part,
        const float* __restrict__ gam, const float* __restrict__ bet,
        const float* __restrict__ cw, const float* __restrict__ cb,
        float* __restrict__ out, float* __restrict__ r1, float* __restrict__ r2,
        float (* __restrict__ cr)[8])
{
    if (blockIdx.x < 32) {
        const int b = blockIdx.x, tid = threadIdx.x;
        float v = 0.f;
#pragma unroll
        for (int si = 0; si < S; ++si)
            v += sysld(part + (size_t)si * 16384 + tid * 32 + b);
        float a = v * __builtin_amdgcn_rcpf(1.f + EXP2F(-v * LOG2E));

        float s1 = a, s2 = a * a;
#pragma unroll
        for (int off = 32; off; off >>= 1) {
            s1 += __shfl_down(s1, off);
            s2 += __shfl_down(s2, off);
        }
        const int lane = tid & 63, wid = tid >> 6;
        if (lane == 0) { r1[wid] = s1; r2[wid] = s2; }
        __syncthreads();
        float t1 = 0.f, t2 = 0.f;
#pragma unroll
        for (int k = 0; k < 8; ++k) { t1 += r1[k]; t2 += r2[k]; }
        float m   = t1 * (1.f / 512.f);
        float var = t2 * (1.f / 512.f) - m * m;
        float r   = __builtin_amdgcn_rsqf(var + LN_EPS);
        float hl  = (a - m) * r * gam[tid] + bet[tid];

#pragma unroll
        for (int c = 0; c < 5; ++c) {
            float pv = hl * cw[c * 512 + tid];
#pragma unroll
            for (int off = 32; off; off >>= 1) pv += __shfl_down(pv, off);
            if (lane == 0) cr[c][wid] = pv;
        }
        __syncthreads();
        if (tid < 5) {
            float sum = 0.f;
#pragma unroll
            for (int k = 0; k < 8; ++k) sum += cr[tid][k];
            out[b * 5 + tid] = sum + cb[tid];
        }
    }
}

// ---------------------------------------------------------------------------
__global__ __launch_bounds__(TPB, 4)
void megakernel(const float* __restrict__ x,
                const float* __restrict__ w0, const float* __restrict__ t0,
                const float* __restrict__ s0, const float* __restrict__ g0,
                const float* __restrict__ b0,
                const float* __restrict__ w1, const float* __restrict__ t1,
                const float* __restrict__ s1, const float* __restrict__ g1,
                const float* __restrict__ b1,
                const float* __restrict__ w2, const float* __restrict__ t2,
                const float* __restrict__ s2, const float* __restrict__ g2,
                const float* __restrict__ b2,
                const float* __restrict__ cw, const float* __restrict__ cb,
                float* __restrict__ out,
                float* __restrict__ part, float* __restrict__ hT,
                int* __restrict__ bar)
{
    __shared__ float4 prep[8][192];             // 24.6 KiB per-wave prep slabs
    __shared__ float  xs[192 * PADX];           // 26.1 KiB x si-slab [i][b]
    __shared__ float  r1[8], r2[8], cr[5][8];   // LN/cls reduction scratch

    const int wave = threadIdx.x >> 6, lane = threadIdx.x & 63;
    const int gw = blockIdx.x * (TPB / 64) + wave;
    float4* myPrep = prep[wave];

    wav0_phase(x, w0, t0, s0, part, myPrep, xs, lane, wave);  // 16384 tasks
    // prefetch layer-1 prep params (complete during barrier + ln0)
    const int o1 = gw & 511, si1 = gw >> 9;
    const size_t off1 = (size_t)o1 * 512 + si1 * 64 + lane;
    float fw1 = w1[off1], ft1 = t1[off1], fs1 = s1[off1];
    gridbar(bar, 1);
    ln_phase<32>(part, g0, b0, hT, r1, r2);
    gridbar(bar, 2);

    wav12_phase(hT, part, myPrep, lane, gw, fw1, ft1, fs1);   // 4096 tasks
    // prefetch layer-2 prep params
    float fw2 = w2[off1], ft2 = t2[off1], fs2 = s2[off1];
    gridbar(bar, 3);
    ln_phase<8>(part, g1, b1, hT, r1, r2);
    gridbar(bar, 4);

    wav12_phase(hT, part, myPrep, lane, gw, fw2, ft2, fs2);
    gridbar(bar, 5);
    cls_phase<8>(part, g2, b2, cw, cb, out, r1, r2, cr);
}

extern "C" void kernel_launch(void* const* d_in, const int* in_sizes, int n_in,
                              void* d_out, int out_size, void* d_ws, size_t ws_size,
                              hipStream_t stream)
{
    const float* x  = (const float*)d_in[0];
    const float* w0 = (const float*)d_in[1];
    const float* t0 = (const float*)d_in[2];
    const float* s0 = (const float*)d_in[3];
    const float* g0 = (const float*)d_in[4];
    const float* b0 = (const float*)d_in[5];
    const float* w1 = (const float*)d_in[6];
    const float* t1 = (const float*)d_in[7];
    const float* s1 = (const float*)d_in[8];
    const float* g1 = (const float*)d_in[9];
    const float* b1 = (const float*)d_in[10];
    const float* w2 = (const float*)d_in[11];
    const float* t2 = (const float*)d_in[12];
    const float* s2 = (const float*)d_in[13];
    const float* g2 = (const float*)d_in[14];
    const float* b2 = (const float*)d_in[15];
    const float* cw = (const float*)d_in[16];
    const float* cb = (const float*)d_in[17];
    float* out = (float*)d_out;

    // ws layout (floats): part 32*16384 (2MB) | hT 16384 | barrier (8KB)
    float* part = (float*)d_ws;
    float* hT   = part + 32 * 16384;
    int*   bar  = (int*)(hT + 16384);

    hipMemsetAsync(bar, 0, 8192, stream);    // capture-safe barrier reset

    void* args[] = { (void*)&x,
                     (void*)&w0, (void*)&t0, (void*)&s0, (void*)&g0, (void*)&b0,
                     (void*)&w1, (void*)&t1, (void*)&s1, (void*)&g1, (void*)&b1,
                     (void*)&w2, (void*)&t2, (void*)&s2, (void*)&g2, (void*)&b2,
                     (void*)&cw, (void*)&cb, (void*)&out,
                     (void*)&part, (void*)&hT, (void*)&bar };

    hipLaunchKernel((const void*)megakernel, dim3(NBLK), dim3(TPB),
                    args, 0, stream);
}